// Round 3
// baseline (264.908 us; speedup 1.0000x reference)
//
#include <hip/hip_runtime.h>

#define N 1024
#define NN (N * N)
#define STRIPS 9           // 9 * 120 = 1080 >= 1024 valid cols (2 cols/lane, 120 valid/wave)
#define SEGS 64            // 64 * 16 = 1024 rows
#define SEGROWS 16
#define NUNITS (STRIPS * SEGS * 8)   // 4608 wave-units
#define NBLOCKS (NUNITS / 4)         // 1152 blocks (%8==0 -> bijective XCD swizzle)

__device__ __forceinline__ int refl(int i) {   // reflect-101
    if (i < 0) return -i;
    if (i >= N) return 2 * N - 2 - i;
    return i;
}

// DPP neighbor moves: VALU-pipe, no DS latency.
// wave_shr:1 (0x138): lane i <- lane i-1  (value from the LEFT column)
// wave_shl:1 (0x130): lane i <- lane i+1  (value from the RIGHT column)
// Boundary lanes get 0 (bound_ctrl) -- confined to discarded halo lanes 0,1,62,63.
__device__ __forceinline__ float dppL(float x) {
    return __int_as_float(__builtin_amdgcn_update_dpp(
        0, __float_as_int(x), 0x138, 0xF, 0xF, true));
}
__device__ __forceinline__ float dppR(float x) {
    return __int_as_float(__builtin_amdgcn_update_dpp(
        0, __float_as_int(x), 0x130, 0xF, 0xF, true));
}

// Per-image rolling state (2 columns). All names static -> registers.
#define DECL_STATE(p) \
  float p##h00=0,p##h01=0,p##h02=0,p##h03=0,p##h04=0;   /* h-blur win col0 */ \
  float p##h10=0,p##h11=0,p##h12=0,p##h13=0,p##h14=0;   /* h-blur win col1 */ \
  float p##bl00=0,p##bl01=0,p##bl02=0;                   /* blur win col0  */ \
  float p##bl10=0,p##bl11=0,p##bl12=0;                   /* blur win col1  */ \
  float p##m00=0,p##m01=0,p##m02=0;                      /* mag win col0   */ \
  float p##m10=0,p##m11=0,p##m12=0;                      /* mag win col1   */ \
  float p##mL0=0,p##mL1=0,p##mL2=0;                      /* mag win c0-1   */ \
  float p##mR0=0,p##mR1=0,p##mR2=0;                      /* mag win c1+1   */ \
  int   p##ax0=0, p##ax1=0, p##axU0=0, p##axU1=0;

// One image's pipeline step at row yv. STAGE: 0=load+hblur, 1=+vblur,
// 2=+sobel/mag/axis (everything but NMS). Compile-time constant -> folds.
#define STEP_IMG(p, base, yv, STAGE) { \
    float g0, g1; \
    if (COLE) { \
      const float* rp = (base); \
      g0 = 0.299f*rp[rc0] + 0.587f*rp[rc0+NN] + 0.114f*rp[rc0+2*NN]; \
      g1 = 0.299f*rp[rc1] + 0.587f*rp[rc1+NN] + 0.114f*rp[rc1+2*NN]; \
    } else { \
      const float2* rp = (const float2*)((base) + c0); \
      float2 v0 = rp[0]; float2 v1 = rp[NN/2]; float2 v2 = rp[NN]; \
      g0 = 0.299f*v0.x + 0.587f*v1.x + 0.114f*v2.x; \
      g1 = 0.299f*v0.y + 0.587f*v1.y + 0.114f*v2.y; \
    } \
    float Lg0 = dppL(g0), Lg1 = dppL(g1), Rg0 = dppR(g0), Rg1 = dppR(g1); \
    float hn0 = w0*Lg0 + w1*Lg1 + w2*g0 + w3*g1 + w4*Rg0; \
    float hn1 = w0*Lg1 + w1*g0 + w2*g1 + w3*Rg0 + w4*Rg1; \
    p##h00=p##h01; p##h01=p##h02; p##h02=p##h03; p##h03=p##h04; p##h04=hn0; \
    p##h10=p##h11; p##h11=p##h12; p##h12=p##h13; p##h13=p##h14; p##h14=hn1; \
    if ((STAGE) >= 1) { \
      float bn0 = w0*p##h00 + w1*p##h01 + w2*p##h02 + w3*p##h03 + w4*p##h04; \
      float bn1 = w0*p##h10 + w1*p##h11 + w2*p##h12 + w3*p##h13 + w4*p##h14; \
      p##bl00=p##bl01; p##bl01=p##bl02; p##bl02=bn0; \
      p##bl10=p##bl11; p##bl11=p##bl12; p##bl12=bn1; \
    } \
    if ((STAGE) >= 2) { \
      float Ar0, Cr0, Ar1, Cr1; \
      if (ROWE) { int z = (yv) - 3; \
        Ar0 = (z == 0)     ? p##bl01 : p##bl00; \
        Cr0 = (z == N - 1) ? p##bl01 : p##bl02; \
        Ar1 = (z == 0)     ? p##bl11 : p##bl10; \
        Cr1 = (z == N - 1) ? p##bl11 : p##bl12; \
      } else { Ar0=p##bl00; Cr0=p##bl02; Ar1=p##bl10; Cr1=p##bl12; } \
      float s0 = Ar0 + 2.f*p##bl01 + Cr0;  float d0 = Cr0 - Ar0; \
      float s1 = Ar1 + 2.f*p##bl11 + Cr1;  float d1 = Cr1 - Ar1; \
      float Ls1 = dppL(s1), Ld1 = dppL(d1), Rs0 = dppR(s0), Rd0 = dppR(d0); \
      if (COLE) { \
        Ls1 = cz0  ? s0 : Ls1;  Ld1 = cz0  ? d0 : Ld1; \
        Rs0 = czN1 ? s1 : Rs0;  Rd0 = czN1 ? d1 : Rd0; \
      } \
      float gx0 = s1 - Ls1;   float gy0 = Ld1 + 2.f*d0 + d1; \
      float gx1 = Rs0 - s0;   float gy1 = d0 + 2.f*d1 + Rd0; \
      float mg0 = sqrtf(gx0*gx0 + gy0*gy0 + 1e-6f); \
      float mg1 = sqrtf(gx1*gx1 + gy1*gy1 + 1e-6f); \
      float ax_, ay_; int cd0, cd1; \
      ax_ = fabsf(gx0); ay_ = fabsf(gy0); \
      cd0 = (ay_ <= 0.41421356f * ax_) ? 0 \
          : (ay_ >= 2.41421356f * ax_) ? 1 \
          : (((gx0 > 0.f) == (gy0 > 0.f)) ? 2 : 3); \
      ax_ = fabsf(gx1); ay_ = fabsf(gy1); \
      cd1 = (ay_ <= 0.41421356f * ax_) ? 0 \
          : (ay_ >= 2.41421356f * ax_) ? 1 \
          : (((gx1 > 0.f) == (gy1 > 0.f)) ? 2 : 3); \
      float Lm1 = dppL(mg1), Rm0 = dppR(mg0); \
      if (COLE) { Lm1 = cz0 ? 0.f : Lm1;  Rm0 = czN1 ? 0.f : Rm0; } \
      p##m00=p##m01; p##m01=p##m02; p##m02=mg0; \
      p##m10=p##m11; p##m11=p##m12; p##m12=mg1; \
      p##mL0=p##mL1; p##mL1=p##mL2; p##mL2=Lm1; \
      p##mR0=p##mR1; p##mR1=p##mR2; p##mR2=Rm0; \
      p##axU0 = p##ax0; p##ax0 = cd0; \
      p##axU1 = p##ax1; p##ax1 = cd1; \
    } \
  }

// NMS for one image at row w = yv-4.
// col0: center=m0*, left=mL*, right=m1*.  col1: center=m1*, left=m0*, right=mR*.
#define NMS_IMG(p, e0, e1, yv) { \
    float z00 = p##m00, zL0 = p##mL0, zC0 = p##m10, zR0 = p##mR0; \
    float z02 = p##m02, zL2 = p##mL2, zC2 = p##m12, zR2 = p##mR2; \
    if (ROWE) { int w = (yv) - 4; \
      if (w == 0)     { z00=0; zL0=0; zC0=0; zR0=0; } \
      if (w == N - 1) { z02=0; zL2=0; zC2=0; zR2=0; } } \
    float n10 = (p##axU0 == 0) ? p##m11 : (p##axU0 == 1) ? z00 \
              : (p##axU0 == 2) ? zC0    : zL0; \
    float n20 = (p##axU0 == 0) ? p##mL1 : (p##axU0 == 1) ? z02 \
              : (p##axU0 == 2) ? zL2    : zC2; \
    float n11 = (p##axU1 == 0) ? p##mR1 : (p##axU1 == 1) ? zC0 \
              : (p##axU1 == 2) ? zR0    : z00; \
    float n21 = (p##axU1 == 0) ? p##m01 : (p##axU1 == 1) ? zC2 \
              : (p##axU1 == 2) ? z02    : zR2; \
    e0 = (p##m01 > n10) && (p##m01 > n20) && (p##m01 > 0.1f); \
    e1 = (p##m11 > n11) && (p##m11 > n21) && (p##m11 > 0.1f); \
  }

#define BODY(yv, STAGE) { \
    int rr = ROWE ? refl(yv) : (yv); \
    const float* ra = A + (size_t)rr * N; \
    const float* rb = B + (size_t)rr * N; \
    STEP_IMG(a, ra, yv, STAGE) \
    STEP_IMG(b, rb, yv, STAGE) \
    if ((STAGE) >= 3) { \
      bool ea0, ea1, eb0, eb1; \
      NMS_IMG(a, ea0, ea1, yv) \
      NMS_IMG(b, eb0, eb1, yv) \
      acc += (int)(valid0 && (ea0 != eb0)); \
      acc += (int)(valid1 && (ea1 != eb1)); \
    } \
  }

template<bool COLE, bool ROWE>
__device__ __forceinline__ void edge_unit(
    const float* __restrict__ op, const float* __restrict__ gt,
    unsigned int* __restrict__ partials,
    int unit, int img, int strip, int seg, int lane)
{
    const float w0 = 0.05448868f, w1 = 0.24420134f, w2 = 0.40261996f,
                w3 = 0.24420134f, w4 = 0.05448868f;

    const int cb = strip * 120 - 4;
    const int c0 = cb + 2 * lane;            // even -> float2-aligned
    const int c1 = c0 + 1;
    const int rc0 = COLE ? refl(c0) : c0;    // scalar reflected indices (COLE only)
    const int rc1 = COLE ? refl(c1) : c1;

    const float* A = op + (size_t)img * 3 * NN;
    const float* B = gt + (size_t)img * 3 * NN;

    const bool cz0  = COLE && (c0 == 0);      // c0 even: only col0 can be 0
    const bool czN1 = COLE && (c1 == N - 1);  // N-1 odd: only col1 can be N-1
    const bool laneok = (lane >= 2) && (lane <= 61);
    const bool valid0 = laneok && (!COLE || ((c0 >= 0) && (c0 < N)));
    const bool valid1 = laneok && (!COLE || ((c1 >= 0) && (c1 < N)));

    DECL_STATE(a)
    DECL_STATE(b)

    int acc = 0;
    const int R0 = seg * SEGROWS;

    if (!ROWE) {
        // staged priming: each stage computes exactly the dataflow subset
        // whose outputs are consumed later (windows fill just-in-time).
#pragma unroll
        for (int y = R0 - 4; y < R0; ++y)     BODY(y, 0)
#pragma unroll
        for (int y = R0; y < R0 + 2; ++y)     BODY(y, 1)
#pragma unroll
        for (int y = R0 + 2; y < R0 + 4; ++y) BODY(y, 2)
    } else {
        // row-edge segs: full (minus NMS) priming, identical to verified kernel
#pragma unroll 2
        for (int y = R0 - 4; y < R0 + 4; ++y) BODY(y, 2)
    }

#pragma unroll 4
    for (int y = R0 + 4; y < R0 + SEGROWS + 4; ++y) BODY(y, 3)

    for (int off = 32; off > 0; off >>= 1)
        acc += __shfl_down(acc, off, 64);
    if (lane == 0)
        partials[unit] = (unsigned int)acc;
}

__global__ __launch_bounds__(256)
void edge_diff_kernel(const float* __restrict__ op, const float* __restrict__ gt,
                      unsigned int* __restrict__ partials)
{
    int lane = threadIdx.x & 63;
    // Bijective XCD-chunked swizzle (1152 blocks = 8 XCDs x 144): each XCD
    // processes a CONTIGUOUS run of units, so seg-neighbors (sharing the
    // 8-row halo) are concurrent on the same XCD's L2.
    int b   = blockIdx.x;
    int swz = (b & 7) * (NBLOCKS / 8) + (b >> 3);
    int unit = swz * 4 + (threadIdx.x >> 6);

    int img  = unit / (STRIPS * SEGS);
    int rem  = unit - img * (STRIPS * SEGS);
    int strip = rem >> 6;            // SEGS = 64
    int seg   = rem & (SEGS - 1);

    bool cole = (strip == 0) || (strip == STRIPS - 1);
    bool rowe = (seg == 0)   || (seg == SEGS - 1);

    if (!cole) {
        if (!rowe) edge_unit<false, false>(op, gt, partials, unit, img, strip, seg, lane);
        else       edge_unit<false, true >(op, gt, partials, unit, img, strip, seg, lane);
    } else {
        if (!rowe) edge_unit<true,  false>(op, gt, partials, unit, img, strip, seg, lane);
        else       edge_unit<true,  true >(op, gt, partials, unit, img, strip, seg, lane);
    }
}

__global__ __launch_bounds__(256)
void finalize_kernel(const unsigned int* __restrict__ partials, float* __restrict__ out)
{
    __shared__ unsigned int ws[4];
    int tid = threadIdx.x;
    unsigned int sum = 0;
    for (int i = tid; i < NUNITS; i += 256)
        sum += partials[i];
    int d = (int)sum;
    for (int off = 32; off > 0; off >>= 1)
        d += __shfl_down(d, off, 64);
    if ((tid & 63) == 0) ws[tid >> 6] = (unsigned int)d;
    __syncthreads();
    if (tid == 0)
        out[0] = (float)(ws[0] + ws[1] + ws[2] + ws[3]) / 8388608.0f;  // 8*1024*1024
}

extern "C" void kernel_launch(void* const* d_in, const int* in_sizes, int n_in,
                              void* d_out, int out_size, void* d_ws, size_t ws_size,
                              hipStream_t stream)
{
    const float* op = (const float*)d_in[0];
    const float* gt = (const float*)d_in[1];
    unsigned int* partials = (unsigned int*)d_ws;   // NUNITS uints, fully overwritten

    edge_diff_kernel<<<dim3(NBLOCKS), dim3(256), 0, stream>>>(op, gt, partials);
    finalize_kernel<<<1, dim3(256), 0, stream>>>(partials, (float*)d_out);
}

// Round 4
// 235.718 us; speedup vs baseline: 1.1238x; 1.1238x over previous
//
#include <hip/hip_runtime.h>

#define N 1024
#define NN (N * N)
#define STRIPS 19          // 18*56 + 16 = 1024 valid cols, 56 valid cols/wave
#define SEGS 32            // 32 * 32 = 1024 rows
#define SEGROWS 32
#define NUNITS (STRIPS * SEGS * 8)   // 4864 wave-units
#define NBLOCKS (NUNITS / 4)         // 1216 four-wave blocks

__device__ __forceinline__ int refl(int i) {   // reflect-101
    if (i < 0) return -i;
    if (i >= N) return 2 * N - 2 - i;
    return i;
}

// Issue the 6 channel loads for row rrv into prefetch slot k (k literal!).
#define LOADROW(k, rrv) { size_t o_ = (size_t)(rrv) * N;                  \
    fAr[k] = Ar[o_]; fAg[k] = Ag[o_]; fAb[k] = Ab[o_];                    \
    fBr[k] = Br[o_]; fBg[k] = Bg[o_]; fBb[k] = Bb[o_]; }

// One row-iteration. Consumes prefetch slot kb (literal), then immediately
// issues the reload for row yv+4 into the same slot (4-iteration load->use
// distance ~= 700-800 cyc of VALU+DS cover for the ~900 cyc HBM miss).
// STAGE: 0=load+hblur, 1=+vblur, 2=+sobel/mag/axis, 3=+NMS. Compile-time.
#define BODY(yv, STAGE, kb, RELOAD) {                                             \
    float ga = 0.299f * fAr[kb] + 0.587f * fAg[kb] + 0.114f * fAb[kb];            \
    float gb = 0.299f * fBr[kb] + 0.587f * fBg[kb] + 0.114f * fBb[kb];            \
    if (RELOAD) { int nx_ = (yv) + 4; int rn_ = ROWE ? refl(nx_) : nx_;           \
                  LOADROW(kb, rn_) }                                              \
    float gal2 = __shfl(ga, iL2, 64), gal1 = __shfl(ga, iL1, 64);                 \
    float gar1 = __shfl(ga, iR1, 64), gar2 = __shfl(ga, iR2, 64);                 \
    float gbl2 = __shfl(gb, iL2, 64), gbl1 = __shfl(gb, iL1, 64);                 \
    float gbr1 = __shfl(gb, iR1, 64), gbr2 = __shfl(gb, iR2, 64);                 \
    float hna = w0*gal2 + w1*gal1 + w2*ga + w3*gar1 + w4*gar2;                    \
    float hnb = w0*gbl2 + w1*gbl1 + w2*gb + w3*gbr1 + w4*gbr2;                    \
    ha0=ha1; ha1=ha2; ha2=ha3; ha3=ha4; ha4=hna;                                  \
    hb0=hb1; hb1=hb2; hb2=hb3; hb3=hb4; hb4=hnb;                                  \
    if ((STAGE) >= 1) {                                                           \
      float bna = w0*ha0 + w1*ha1 + w2*ha2 + w3*ha3 + w4*ha4;                     \
      float bnb = w0*hb0 + w1*hb1 + w2*hb2 + w3*hb3 + w4*hb4;                     \
      bla0=bla1; bla1=bla2; bla2=bna;                                             \
      blb0=blb1; blb1=blb2; blb2=bnb;                                             \
    }                                                                             \
    if ((STAGE) >= 2) {                                                           \
      float Ara, Cra, Arb, Crb;                                                   \
      if (ROWE) {                                                                 \
        int z = (yv) - 3;                                                         \
        Ara = (z == 0)     ? bla1 : bla0;                                         \
        Cra = (z == N - 1) ? bla1 : bla2;                                         \
        Arb = (z == 0)     ? blb1 : blb0;                                         \
        Crb = (z == N - 1) ? blb1 : blb2;                                         \
      } else { Ara = bla0; Cra = bla2; Arb = blb0; Crb = blb2; }                  \
      float sa = Ara + 2.f*bla1 + Cra;  float da = Cra - Ara;                     \
      float sb = Arb + 2.f*blb1 + Crb;  float db = Crb - Arb;                     \
      float sal = __shfl(sa, iL1, 64), sar = __shfl(sa, iR1, 64);                 \
      float dal = __shfl(da, iL1, 64), dar = __shfl(da, iR1, 64);                 \
      float sbl = __shfl(sb, iL1, 64), sbr = __shfl(sb, iR1, 64);                 \
      float dbl = __shfl(db, iL1, 64), dbr = __shfl(db, iR1, 64);                 \
      if (COLE) {                                                                 \
        sal = cz0 ? sa : sal;  dal = cz0 ? da : dal;                              \
        sar = czN ? sa : sar;  dar = czN ? da : dar;                              \
        sbl = cz0 ? sb : sbl;  dbl = cz0 ? db : dbl;                              \
        sbr = czN ? sb : sbr;  dbr = czN ? db : dbr;                              \
      }                                                                           \
      float gxa = sar - sal;            float gya = dal + 2.f*da + dar;           \
      float gxb = sbr - sbl;            float gyb = dbl + 2.f*db + dbr;           \
      float maga = sqrtf(gxa*gxa + gya*gya + 1e-6f);                              \
      float magb = sqrtf(gxb*gxb + gyb*gyb + 1e-6f);                              \
      float axx = fabsf(gxa), ayy = fabsf(gya);                                   \
      int cda = (ayy <= 0.41421356f * axx) ? 0                                    \
              : (ayy >= 2.41421356f * axx) ? 1                                    \
              : (((gxa > 0.f) == (gya > 0.f)) ? 2 : 3);                           \
      float bxx = fabsf(gxb), byy = fabsf(gyb);                                   \
      int cdb = (byy <= 0.41421356f * bxx) ? 0                                    \
              : (byy >= 2.41421356f * bxx) ? 1                                    \
              : (((gxb > 0.f) == (gyb > 0.f)) ? 2 : 3);                           \
      float mala = __shfl(maga, iL1, 64); if (COLE) mala = cz0 ? 0.f : mala;      \
      float mara = __shfl(maga, iR1, 64); if (COLE) mara = czN ? 0.f : mara;      \
      float malb = __shfl(magb, iL1, 64); if (COLE) malb = cz0 ? 0.f : malb;      \
      float marb = __shfl(magb, iR1, 64); if (COLE) marb = czN ? 0.f : marb;      \
      mga0=mga1;   mga1=mga2;   mga2=maga;                                        \
      mgla0=mgla1; mgla1=mgla2; mgla2=mala;                                       \
      mgra0=mgra1; mgra1=mgra2; mgra2=mara;                                       \
      mgb0=mgb1;   mgb1=mgb2;   mgb2=magb;                                        \
      mglb0=mglb1; mglb1=mglb2; mglb2=malb;                                       \
      mgrb0=mgrb1; mgrb1=mgrb2; mgrb2=marb;                                       \
      int axUa = axa; axa = cda;                                                  \
      int axUb = axb; axb = cdb;                                                  \
      if ((STAGE) >= 3) {                                                         \
        float m0a = mga0, l0a = mgla0, r0a = mgra0;                               \
        float m2a = mga2, l2a = mgla2, r2a = mgra2;                               \
        float m0b = mgb0, l0b = mglb0, r0b = mgrb0;                               \
        float m2b = mgb2, l2b = mglb2, r2b = mgrb2;                               \
        if (ROWE) {                                                               \
          int w = (yv) - 4;                                                       \
          if (w == 0)     { m0a=0; l0a=0; r0a=0; m0b=0; l0b=0; r0b=0; }           \
          if (w == N - 1) { m2a=0; l2a=0; r2a=0; m2b=0; l2b=0; r2b=0; }           \
        }                                                                         \
        float n1a = (axUa == 0) ? mgra1 : (axUa == 1) ? m0a : (axUa == 2) ? r0a : l0a; \
        float n2a = (axUa == 0) ? mgla1 : (axUa == 1) ? m2a : (axUa == 2) ? l2a : r2a; \
        float n1b = (axUb == 0) ? mgrb1 : (axUb == 1) ? m0b : (axUb == 2) ? r0b : l0b; \
        float n2b = (axUb == 0) ? mglb1 : (axUb == 1) ? m2b : (axUb == 2) ? l2b : r2b; \
        bool ea = (mga1 > n1a) && (mga1 > n2a) && (mga1 > 0.1f);                  \
        bool eb = (mgb1 > n1b) && (mgb1 > n2b) && (mgb1 > 0.1f);                  \
        acc += (int)(valid && (ea != eb));                                        \
      }                                                                           \
    }                                                                             \
  }

template<bool COLE, bool ROWE>
__device__ __forceinline__ void edge_unit(
    const float* __restrict__ op, const float* __restrict__ gt,
    unsigned int* __restrict__ partials,
    int unit, int img, int strip, int seg, int lane)
{
    const float w0 = 0.05448868f, w1 = 0.24420134f, w2 = 0.40261996f,
                w3 = 0.24420134f, w4 = 0.05448868f;

    const int cb = strip * 56 - 4;
    const int c  = cb + lane;
    const int cR = COLE ? refl(c) : c;

    const float* Ar = op + (size_t)img * 3 * NN + cR;
    const float* Ag = Ar + NN;
    const float* Ab = Ar + 2 * NN;
    const float* Br = gt + (size_t)img * 3 * NN + cR;
    const float* Bg = Br + NN;
    const float* Bb = Br + 2 * NN;

    const bool cz0 = COLE && (c == 0);
    const bool czN = COLE && (c == N - 1);
    const bool valid = (lane >= 4) && (lane <= 59) &&
                       (!COLE || ((c >= 0) && (c < N)));

    const int iL1 = lane - 1, iL2 = lane - 2, iR1 = lane + 1, iR2 = lane + 2;

    // rolling windows, image A
    float ha0=0,ha1=0,ha2=0,ha3=0,ha4=0;
    float bla0=0,bla1=0,bla2=0;
    float mga0=0,mga1=0,mga2=0;
    float mgla0=0,mgla1=0,mgla2=0;
    float mgra0=0,mgra1=0,mgra2=0;
    int   axa = 0;
    // image B
    float hb0=0,hb1=0,hb2=0,hb3=0,hb4=0;
    float blb0=0,blb1=0,blb2=0;
    float mgb0=0,mgb1=0,mgb2=0;
    float mglb0=0,mglb1=0,mglb2=0;
    float mgrb0=0,mgrb1=0,mgrb2=0;
    int   axb = 0;

    // 4-deep rotating prefetch file (all indices literal -> registers)
    float fAr[4], fAg[4], fAb[4], fBr[4], fBg[4], fBb[4];

    int acc = 0;
    const int R0 = seg * SEGROWS;

    if (!ROWE) {
        // interior rows: R0-4 >= 28, no reflection anywhere
        LOADROW(0, R0 - 4) LOADROW(1, R0 - 3) LOADROW(2, R0 - 2) LOADROW(3, R0 - 1)
        // staged priming (exact dataflow subset; outputs unused stages skipped)
        BODY(R0 - 4, 0, 0, 1) BODY(R0 - 3, 0, 1, 1)
        BODY(R0 - 2, 0, 2, 1) BODY(R0 - 1, 0, 3, 1)
        BODY(R0,     1, 0, 1) BODY(R0 + 1, 1, 1, 1)
        BODY(R0 + 2, 2, 2, 1) BODY(R0 + 3, 2, 3, 1)
    } else {
        LOADROW(0, refl(R0 - 4)) LOADROW(1, refl(R0 - 3))
        LOADROW(2, refl(R0 - 2)) LOADROW(3, refl(R0 - 1))
        // row-edge segs: full stage-2 priming (bit-identical to verified kernel)
        BODY(R0 - 4, 2, 0, 1) BODY(R0 - 3, 2, 1, 1)
        BODY(R0 - 2, 2, 2, 1) BODY(R0 - 1, 2, 3, 1)
        BODY(R0,     2, 0, 1) BODY(R0 + 1, 2, 1, 1)
        BODY(R0 + 2, 2, 2, 1) BODY(R0 + 3, 2, 3, 1)
    }

    // main: 28 output rows with reload (explicit literal slot ids), then 4 without.
    for (int jj = 8; jj < 36; jj += 4) {
        int y = R0 - 4 + jj;
        BODY(y,     3, 0, 1)
        BODY(y + 1, 3, 1, 1)
        BODY(y + 2, 3, 2, 1)
        BODY(y + 3, 3, 3, 1)
    }
    {
        int y = R0 + 32;
        BODY(y,     3, 0, 0)
        BODY(y + 1, 3, 1, 0)
        BODY(y + 2, 3, 2, 0)
        BODY(y + 3, 3, 3, 0)
    }

    for (int off = 32; off > 0; off >>= 1)
        acc += __shfl_down(acc, off, 64);
    if (lane == 0)
        partials[unit] = (unsigned int)acc;
}

__global__ __launch_bounds__(256)
void edge_diff_kernel(const float* __restrict__ op, const float* __restrict__ gt,
                      unsigned int* __restrict__ partials)
{
    int lane = threadIdx.x & 63;
    // IDENTITY unit order (seg fastest, then strip, then img) — the verified
    // low-FETCH scan order; no XCD swizzle (round-3 evidence: it cost +21 MB).
    int unit = blockIdx.x * 4 + (threadIdx.x >> 6);
    int img  = unit / (STRIPS * SEGS);
    int rem  = unit - img * (STRIPS * SEGS);
    int strip = rem >> 5;            // SEGS = 32
    int seg   = rem & (SEGS - 1);

    bool cole = (strip == 0) || (strip == STRIPS - 1);
    bool rowe = (seg == 0)   || (seg == SEGS - 1);

    if (!cole) {
        if (!rowe) edge_unit<false, false>(op, gt, partials, unit, img, strip, seg, lane);
        else       edge_unit<false, true >(op, gt, partials, unit, img, strip, seg, lane);
    } else {
        if (!rowe) edge_unit<true,  false>(op, gt, partials, unit, img, strip, seg, lane);
        else       edge_unit<true,  true >(op, gt, partials, unit, img, strip, seg, lane);
    }
}

__global__ __launch_bounds__(256)
void finalize_kernel(const unsigned int* __restrict__ partials, float* __restrict__ out)
{
    __shared__ unsigned int ws[4];
    int tid = threadIdx.x;
    unsigned int sum = 0;
    for (int i = tid; i < NUNITS; i += 256)
        sum += partials[i];
    int d = (int)sum;
    for (int off = 32; off > 0; off >>= 1)
        d += __shfl_down(d, off, 64);
    if ((tid & 63) == 0) ws[tid >> 6] = (unsigned int)d;
    __syncthreads();
    if (tid == 0)
        out[0] = (float)(ws[0] + ws[1] + ws[2] + ws[3]) / 8388608.0f;  // 8*1024*1024
}

extern "C" void kernel_launch(void* const* d_in, const int* in_sizes, int n_in,
                              void* d_out, int out_size, void* d_ws, size_t ws_size,
                              hipStream_t stream)
{
    const float* op = (const float*)d_in[0];
    const float* gt = (const float*)d_in[1];
    unsigned int* partials = (unsigned int*)d_ws;   // NUNITS uints, fully overwritten

    edge_diff_kernel<<<dim3(NBLOCKS), dim3(256), 0, stream>>>(op, gt, partials);
    finalize_kernel<<<1, dim3(256), 0, stream>>>(partials, (float*)d_out);
}

// Round 5
// 233.954 us; speedup vs baseline: 1.1323x; 1.0075x over previous
//
#include <hip/hip_runtime.h>

#define N 1024
#define NN (N * N)
#define STRIPS 19          // 18*56 + 16 = 1024 valid cols, 56 valid cols/wave
#define SEGS 32            // 32 * 32 = 1024 rows
#define SEGROWS 32
#define NUNITS (STRIPS * SEGS * 8)   // 4864 wave-units
#define NBLOCKS (NUNITS / 4)         // 1216 four-wave blocks

__device__ __forceinline__ int refl(int i) {   // reflect-101
    if (i < 0) return -i;
    if (i >= N) return 2 * N - 2 - i;
    return i;
}

// Issue the 6 channel loads for row rrv into prefetch slot k (k literal).
#define LOADROW(k, rrv) { size_t o_ = (size_t)(rrv) * N;                  \
    fAr[k] = Ar[o_]; fAg[k] = Ag[o_]; fAb[k] = Ab[o_];                    \
    fBr[k] = Br[o_]; fBg[k] = Bg[o_]; fBb[k] = Bb[o_]; }

// NMS for one output row. c = center mag, cl/cr = center-row left/right,
// p* = row w-1 (mag,left,right), n* = row w+1, ax = axis at row w.
// Expressions literal from the verified kernel.
#define NMS1(ea, c, cl, cr, pm, pl, pr, nm, nl, nr, ax) {                         \
    float n1_ = ((ax) == 0) ? (cr) : ((ax) == 1) ? (pm) : ((ax) == 2) ? (pr) : (pl); \
    float n2_ = ((ax) == 0) ? (cl) : ((ax) == 1) ? (nm) : ((ax) == 2) ? (nl) : (nr); \
    ea = ((c) > n1_) && ((c) > n2_) && ((c) > 0.1f); }

// PAIR: process rows (yv, yv+1) in one iteration. All shuffles for both rows
// issue back-to-back so the 2nd row's DS latency hides under the 1st row's
// dependent VALU. STAGE: 0=load+hblur, 1=+vblur, 2=+sobel/mag/axis, 3=+NMS.
// Window mapping on entry: ah0..ah3 = h(y-4..y-1); abl0,abl1 = bl(y-4),bl(y-3);
// am0,am1 (+L,R) = mag(y-5),mag(y-4); axPa = ax(y-4).  (same for image b)
#define PAIR(yv, STAGE, k0, k1, RELOAD) {                                         \
    float ga0 = 0.299f*fAr[k0] + 0.587f*fAg[k0] + 0.114f*fAb[k0];                 \
    float gb0 = 0.299f*fBr[k0] + 0.587f*fBg[k0] + 0.114f*fBb[k0];                 \
    float ga1 = 0.299f*fAr[k1] + 0.587f*fAg[k1] + 0.114f*fAb[k1];                 \
    float gb1 = 0.299f*fBr[k1] + 0.587f*fBg[k1] + 0.114f*fBb[k1];                 \
    if (RELOAD) {                                                                 \
        int n0_ = (yv) + 4, n1_ = (yv) + 5;                                       \
        int r0_ = ROWE ? refl(n0_) : n0_;                                         \
        int r1_ = ROWE ? refl(n1_) : n1_;                                         \
        LOADROW(k0, r0_) LOADROW(k1, r1_)                                         \
    }                                                                             \
    /* 16 gray shuffles issued together */                                        \
    float a0l2=__shfl(ga0,iL2,64), a0l1=__shfl(ga0,iL1,64);                       \
    float a0r1=__shfl(ga0,iR1,64), a0r2=__shfl(ga0,iR2,64);                       \
    float b0l2=__shfl(gb0,iL2,64), b0l1=__shfl(gb0,iL1,64);                       \
    float b0r1=__shfl(gb0,iR1,64), b0r2=__shfl(gb0,iR2,64);                       \
    float a1l2=__shfl(ga1,iL2,64), a1l1=__shfl(ga1,iL1,64);                       \
    float a1r1=__shfl(ga1,iR1,64), a1r2=__shfl(ga1,iR2,64);                       \
    float b1l2=__shfl(gb1,iL2,64), b1l1=__shfl(gb1,iL1,64);                       \
    float b1r1=__shfl(gb1,iR1,64), b1r2=__shfl(gb1,iR2,64);                       \
    ah4 = w0*a0l2 + w1*a0l1 + w2*ga0 + w3*a0r1 + w4*a0r2;                         \
    bh4 = w0*b0l2 + w1*b0l1 + w2*gb0 + w3*b0r1 + w4*b0r2;                         \
    ah5 = w0*a1l2 + w1*a1l1 + w2*ga1 + w3*a1r1 + w4*a1r2;                         \
    bh5 = w0*b1l2 + w1*b1l1 + w2*gb1 + w3*b1r1 + w4*b1r2;                         \
    if ((STAGE) >= 1) {                                                           \
      abl2 = w0*ah0 + w1*ah1 + w2*ah2 + w3*ah3 + w4*ah4;   /* bl(y-2) */          \
      abl3 = w0*ah1 + w1*ah2 + w2*ah3 + w3*ah4 + w4*ah5;   /* bl(y-1) */          \
      bbl2 = w0*bh0 + w1*bh1 + w2*bh2 + w3*bh3 + w4*bh4;                          \
      bbl3 = w0*bh1 + w1*bh2 + w2*bh3 + w3*bh4 + w4*bh5;                          \
      if ((STAGE) >= 2) {                                                         \
        int z0_ = (yv) - 3, z1_ = (yv) - 2;                                       \
        float Aa0, Ca0, Ab0, Cb0, Aa1, Ca1, Ab1, Cb1;                             \
        if (ROWE) {                                                               \
          Aa0 = (z0_ == 0)     ? abl1 : abl0;                                     \
          Ca0 = (z0_ == N - 1) ? abl1 : abl2;                                     \
          Ab0 = (z0_ == 0)     ? bbl1 : bbl0;                                     \
          Cb0 = (z0_ == N - 1) ? bbl1 : bbl2;                                     \
          Aa1 = (z1_ == 0)     ? abl2 : abl1;                                     \
          Ca1 = (z1_ == N - 1) ? abl2 : abl3;                                     \
          Ab1 = (z1_ == 0)     ? bbl2 : bbl1;                                     \
          Cb1 = (z1_ == N - 1) ? bbl2 : bbl3;                                     \
        } else { Aa0=abl0; Ca0=abl2; Ab0=bbl0; Cb0=bbl2;                          \
                 Aa1=abl1; Ca1=abl3; Ab1=bbl1; Cb1=bbl3; }                        \
        float sa0 = Aa0 + 2.f*abl1 + Ca0;  float da0 = Ca0 - Aa0;                 \
        float sb0 = Ab0 + 2.f*bbl1 + Cb0;  float db0 = Cb0 - Ab0;                 \
        float sa1 = Aa1 + 2.f*abl2 + Ca1;  float da1 = Ca1 - Aa1;                 \
        float sb1 = Ab1 + 2.f*bbl2 + Cb1;  float db1 = Cb1 - Ab1;                 \
        /* 16 sobel shuffles issued together */                                   \
        float sa0l=__shfl(sa0,iL1,64), sa0r=__shfl(sa0,iR1,64);                   \
        float da0l=__shfl(da0,iL1,64), da0r=__shfl(da0,iR1,64);                   \
        float sb0l=__shfl(sb0,iL1,64), sb0r=__shfl(sb0,iR1,64);                   \
        float db0l=__shfl(db0,iL1,64), db0r=__shfl(db0,iR1,64);                   \
        float sa1l=__shfl(sa1,iL1,64), sa1r=__shfl(sa1,iR1,64);                   \
        float da1l=__shfl(da1,iL1,64), da1r=__shfl(da1,iR1,64);                   \
        float sb1l=__shfl(sb1,iL1,64), sb1r=__shfl(sb1,iR1,64);                   \
        float db1l=__shfl(db1,iL1,64), db1r=__shfl(db1,iR1,64);                   \
        if (COLE) {                                                               \
          sa0l = cz0 ? sa0 : sa0l;  da0l = cz0 ? da0 : da0l;                      \
          sa0r = czN ? sa0 : sa0r;  da0r = czN ? da0 : da0r;                      \
          sb0l = cz0 ? sb0 : sb0l;  db0l = cz0 ? db0 : db0l;                      \
          sb0r = czN ? sb0 : sb0r;  db0r = czN ? db0 : db0r;                      \
          sa1l = cz0 ? sa1 : sa1l;  da1l = cz0 ? da1 : da1l;                      \
          sa1r = czN ? sa1 : sa1r;  da1r = czN ? da1 : da1r;                      \
          sb1l = cz0 ? sb1 : sb1l;  db1l = cz0 ? db1 : db1l;                      \
          sb1r = czN ? sb1 : sb1r;  db1r = czN ? db1 : db1r;                      \
        }                                                                         \
        float gxa0 = sa0r - sa0l;  float gya0 = da0l + 2.f*da0 + da0r;            \
        float gxb0 = sb0r - sb0l;  float gyb0 = db0l + 2.f*db0 + db0r;            \
        float gxa1 = sa1r - sa1l;  float gya1 = da1l + 2.f*da1 + da1r;            \
        float gxb1 = sb1r - sb1l;  float gyb1 = db1l + 2.f*db1 + db1r;            \
        float ma0 = sqrtf(gxa0*gxa0 + gya0*gya0 + 1e-6f);                         \
        float mb0 = sqrtf(gxb0*gxb0 + gyb0*gyb0 + 1e-6f);                         \
        float ma1 = sqrtf(gxa1*gxa1 + gya1*gya1 + 1e-6f);                         \
        float mb1 = sqrtf(gxb1*gxb1 + gyb1*gyb1 + 1e-6f);                         \
        float x_, yy_;                                                            \
        x_ = fabsf(gxa0); yy_ = fabsf(gya0);                                      \
        int cda0 = (yy_ <= 0.41421356f * x_) ? 0                                  \
                 : (yy_ >= 2.41421356f * x_) ? 1                                  \
                 : (((gxa0 > 0.f) == (gya0 > 0.f)) ? 2 : 3);                      \
        x_ = fabsf(gxb0); yy_ = fabsf(gyb0);                                      \
        int cdb0 = (yy_ <= 0.41421356f * x_) ? 0                                  \
                 : (yy_ >= 2.41421356f * x_) ? 1                                  \
                 : (((gxb0 > 0.f) == (gyb0 > 0.f)) ? 2 : 3);                      \
        x_ = fabsf(gxa1); yy_ = fabsf(gya1);                                      \
        int cda1 = (yy_ <= 0.41421356f * x_) ? 0                                  \
                 : (yy_ >= 2.41421356f * x_) ? 1                                  \
                 : (((gxa1 > 0.f) == (gya1 > 0.f)) ? 2 : 3);                      \
        x_ = fabsf(gxb1); yy_ = fabsf(gyb1);                                      \
        int cdb1 = (yy_ <= 0.41421356f * x_) ? 0                                  \
                 : (yy_ >= 2.41421356f * x_) ? 1                                  \
                 : (((gxb1 > 0.f) == (gyb1 > 0.f)) ? 2 : 3);                      \
        /* 8 mag shuffles issued together */                                      \
        float ma0L=__shfl(ma0,iL1,64), ma0R=__shfl(ma0,iR1,64);                   \
        float mb0L=__shfl(mb0,iL1,64), mb0R=__shfl(mb0,iR1,64);                   \
        float ma1L=__shfl(ma1,iL1,64), ma1R=__shfl(ma1,iR1,64);                   \
        float mb1L=__shfl(mb1,iL1,64), mb1R=__shfl(mb1,iR1,64);                   \
        if (COLE) {                                                               \
          ma0L = cz0 ? 0.f : ma0L;  ma0R = czN ? 0.f : ma0R;                      \
          mb0L = cz0 ? 0.f : mb0L;  mb0R = czN ? 0.f : mb0R;                      \
          ma1L = cz0 ? 0.f : ma1L;  ma1R = czN ? 0.f : ma1R;                      \
          mb1L = cz0 ? 0.f : mb1L;  mb1R = czN ? 0.f : mb1R;                      \
        }                                                                         \
        am2 = ma0; am3 = ma1; amL2 = ma0L; amL3 = ma1L; amR2 = ma0R; amR3 = ma1R; \
        bm2 = mb0; bm3 = mb1; bmL2 = mb0L; bmL3 = mb1L; bmR2 = mb0R; bmR3 = mb1R; \
        if ((STAGE) >= 3) {                                                       \
          int w0_ = (yv) - 4, w1_ = (yv) - 3;                                     \
          /* w0 even, w1 odd (R0 even) => only w0 can be 0, only w1 can be N-1 */ \
          float pa_m=am0, pa_l=amL0, pa_r=amR0;                                   \
          float pb_m=bm0, pb_l=bmL0, pb_r=bmR0;                                   \
          if (ROWE && w0_ == 0) { pa_m=0; pa_l=0; pa_r=0; pb_m=0; pb_l=0; pb_r=0; } \
          bool ea0, eb0, ea1, eb1;                                                \
          NMS1(ea0, am1, amL1, amR1, pa_m, pa_l, pa_r, am2, amL2, amR2, axPa)     \
          NMS1(eb0, bm1, bmL1, bmR1, pb_m, pb_l, pb_r, bm2, bmL2, bmR2, axPb)     \
          float qa_m=am3, qa_l=amL3, qa_r=amR3;                                   \
          float qb_m=bm3, qb_l=bmL3, qb_r=bmR3;                                   \
          if (ROWE && w1_ == N - 1) { qa_m=0; qa_l=0; qa_r=0; qb_m=0; qb_l=0; qb_r=0; } \
          NMS1(ea1, am2, amL2, amR2, am1, amL1, amR1, qa_m, qa_l, qa_r, cda0)     \
          NMS1(eb1, bm2, bmL2, bmR2, bm1, bmL1, bmR1, qb_m, qb_l, qb_r, cdb0)     \
          acc += (int)(valid && (ea0 != eb0));                                    \
          acc += (int)(valid && (ea1 != eb1));                                    \
        }                                                                         \
        am0 = am2; am1 = am3; amL0 = amL2; amL1 = amL3; amR0 = amR2; amR1 = amR3; \
        bm0 = bm2; bm1 = bm3; bmL0 = bmL2; bmL1 = bmL3; bmR0 = bmR2; bmR1 = bmR3; \
        axPa = cda1; axPb = cdb1;                                                 \
      }                                                                           \
      abl0 = abl2; abl1 = abl3;                                                   \
      bbl0 = bbl2; bbl1 = bbl3;                                                   \
    }                                                                             \
    ah0 = ah2; ah1 = ah3; ah2 = ah4; ah3 = ah5;                                   \
    bh0 = bh2; bh1 = bh3; bh2 = bh4; bh3 = bh5;                                   \
  }

template<bool COLE, bool ROWE>
__device__ __forceinline__ void edge_unit(
    const float* __restrict__ op, const float* __restrict__ gt,
    unsigned int* __restrict__ partials,
    int unit, int img, int strip, int seg, int lane)
{
    const float w0 = 0.05448868f, w1 = 0.24420134f, w2 = 0.40261996f,
                w3 = 0.24420134f, w4 = 0.05448868f;

    const int cb = strip * 56 - 4;
    const int c  = cb + lane;
    const int cR = COLE ? refl(c) : c;

    const float* Ar = op + (size_t)img * 3 * NN + cR;
    const float* Ag = Ar + NN;
    const float* Ab = Ar + 2 * NN;
    const float* Br = gt + (size_t)img * 3 * NN + cR;
    const float* Bg = Br + NN;
    const float* Bb = Br + 2 * NN;

    const bool cz0 = COLE && (c == 0);
    const bool czN = COLE && (c == N - 1);
    const bool valid = (lane >= 4) && (lane <= 59) &&
                       (!COLE || ((c >= 0) && (c < N)));

    const int iL1 = lane - 1, iL2 = lane - 2, iR1 = lane + 1, iR2 = lane + 2;

    // rolling windows (pair-stride layout; see PAIR header comment)
    float ah0=0,ah1=0,ah2=0,ah3=0,ah4=0,ah5=0;
    float bh0=0,bh1=0,bh2=0,bh3=0,bh4=0,bh5=0;
    float abl0=0,abl1=0,abl2=0,abl3=0;
    float bbl0=0,bbl1=0,bbl2=0,bbl3=0;
    float am0=0,am1=0,am2=0,am3=0, amL0=0,amL1=0,amL2=0,amL3=0, amR0=0,amR1=0,amR2=0,amR3=0;
    float bm0=0,bm1=0,bm2=0,bm3=0, bmL0=0,bmL1=0,bmL2=0,bmL3=0, bmR0=0,bmR1=0,bmR2=0,bmR3=0;
    int axPa=0, axPb=0;

    // 4-deep rotating prefetch file (literal indices -> registers)
    float fAr[4], fAg[4], fAb[4], fBr[4], fBg[4], fBb[4];

    int acc = 0;
    const int R0 = seg * SEGROWS;

    if (!ROWE) {
        LOADROW(0, R0 - 4) LOADROW(1, R0 - 3) LOADROW(2, R0 - 2) LOADROW(3, R0 - 1)
        // staged priming (exact dataflow subset)
        PAIR(R0 - 4, 0, 0, 1, 1)
        PAIR(R0 - 2, 0, 2, 3, 1)
        PAIR(R0,     1, 0, 1, 1)
        PAIR(R0 + 2, 2, 2, 3, 1)
    } else {
        LOADROW(0, refl(R0 - 4)) LOADROW(1, refl(R0 - 3))
        LOADROW(2, refl(R0 - 2)) LOADROW(3, refl(R0 - 1))
        // row-edge segs: full stage-2 priming (matches verified kernel)
        PAIR(R0 - 4, 2, 0, 1, 1)
        PAIR(R0 - 2, 2, 2, 3, 1)
        PAIR(R0,     2, 0, 1, 1)
        PAIR(R0 + 2, 2, 2, 3, 1)
    }

    // main: 14 reload pairs (rows R0+4 .. R0+31 outputs), then 2 tail pairs
#pragma unroll 1
    for (int t = 0; t < 7; ++t) {
        int y = R0 + 4 + t * 4;
        PAIR(y,     3, 0, 1, 1)
        PAIR(y + 2, 3, 2, 3, 1)
    }
    PAIR(R0 + 32, 3, 0, 1, 0)
    PAIR(R0 + 34, 3, 2, 3, 0)

    for (int off = 32; off > 0; off >>= 1)
        acc += __shfl_down(acc, off, 64);
    if (lane == 0)
        partials[unit] = (unsigned int)acc;
}

__global__ __launch_bounds__(256)
void edge_diff_kernel(const float* __restrict__ op, const float* __restrict__ gt,
                      unsigned int* __restrict__ partials)
{
    int lane = threadIdx.x & 63;
    // IDENTITY unit order (seg fastest) — the verified low-FETCH scan order.
    int unit = blockIdx.x * 4 + (threadIdx.x >> 6);
    int img  = unit / (STRIPS * SEGS);
    int rem  = unit - img * (STRIPS * SEGS);
    int strip = rem >> 5;            // SEGS = 32
    int seg   = rem & (SEGS - 1);

    bool cole = (strip == 0) || (strip == STRIPS - 1);
    bool rowe = (seg == 0)   || (seg == SEGS - 1);

    if (!cole) {
        if (!rowe) edge_unit<false, false>(op, gt, partials, unit, img, strip, seg, lane);
        else       edge_unit<false, true >(op, gt, partials, unit, img, strip, seg, lane);
    } else {
        if (!rowe) edge_unit<true,  false>(op, gt, partials, unit, img, strip, seg, lane);
        else       edge_unit<true,  true >(op, gt, partials, unit, img, strip, seg, lane);
    }
}

__global__ __launch_bounds__(256)
void finalize_kernel(const unsigned int* __restrict__ partials, float* __restrict__ out)
{
    __shared__ unsigned int ws[4];
    int tid = threadIdx.x;
    unsigned int sum = 0;
    for (int i = tid; i < NUNITS; i += 256)
        sum += partials[i];
    int d = (int)sum;
    for (int off = 32; off > 0; off >>= 1)
        d += __shfl_down(d, off, 64);
    if ((tid & 63) == 0) ws[tid >> 6] = (unsigned int)d;
    __syncthreads();
    if (tid == 0)
        out[0] = (float)(ws[0] + ws[1] + ws[2] + ws[3]) / 8388608.0f;  // 8*1024*1024
}

extern "C" void kernel_launch(void* const* d_in, const int* in_sizes, int n_in,
                              void* d_out, int out_size, void* d_ws, size_t ws_size,
                              hipStream_t stream)
{
    const float* op = (const float*)d_in[0];
    const float* gt = (const float*)d_in[1];
    unsigned int* partials = (unsigned int*)d_ws;   // NUNITS uints, fully overwritten

    edge_diff_kernel<<<dim3(NBLOCKS), dim3(256), 0, stream>>>(op, gt, partials);
    finalize_kernel<<<1, dim3(256), 0, stream>>>(partials, (float*)d_out);
}